// Round 8
// baseline (169.597 us; speedup 1.0000x reference)
//
#include <hip/hip_runtime.h>
#include <hip/hip_bf16.h>

typedef __attribute__((ext_vector_type(8))) short short8;
typedef __attribute__((ext_vector_type(4))) float f32x4;

#define B_  8
#define T_  2048
#define C_  768
#define H_  64
#define M_  (B_ * T_)   // 16384 rows

// direct global -> LDS, 16 B per lane; LDS dest must be wave-uniform base.
#define GLDS16(g, l) __builtin_amdgcn_global_load_lds(                        \
    (const __attribute__((address_space(1))) void*)(g),                       \
    (__attribute__((address_space(3))) void*)(l), 16, 0, 0)

static __device__ __forceinline__ unsigned short f2bf(float f) {
    __hip_bfloat16 h = __float2bfloat16(f);
    return *reinterpret_cast<unsigned short*>(&h);
}

static __device__ __forceinline__ short8 make_frag(const unsigned short* p0, const unsigned short* p1) {
    const ushort4 a = *reinterpret_cast<const ushort4*>(p0);
    const ushort4 b = *reinterpret_cast<const ushort4*>(p1);
    short8 r;
    r[0] = (short)a.x; r[1] = (short)a.y; r[2] = (short)a.z; r[3] = (short)a.w;
    r[4] = (short)b.x; r[5] = (short)b.y; r[6] = (short)b.z; r[7] = (short)b.w;
    return r;
}

// XOR swizzle for 64-ushort (128 B) rows: permute 16 B chunk idx with row&7.
static __device__ __forceinline__ int swz(int row, int u) {
    return row * 64 + ((((u) >> 3) ^ (row & 7)) << 3) + (u & 7);
}

// Fragment-order position of element k (0..63) within a 64-elem image row.
static __device__ __forceinline__ int fragoff(int k) {
    const int half = k >> 5;
    const int kk   = k & 31;
    const int c    = half * 4 + ((kk >> 2) & 3);
    const int p    = (kk & 3) + ((kk & 16) >> 2);
    return c * 8 + p;
}

#define LOG2E_SCALE 0.18033688011112042f   // 0.125 * log2(e), folded into Wq

// ---------------------------------------------------------------------------
// Kernel 0: W -> Wt (transpose + fp32->bf16), Wq pre-scaled; zero merge ctrs.
// ---------------------------------------------------------------------------
__global__ __launch_bounds__(256) void prep_w(
    const float* __restrict__ Wq, const float* __restrict__ Wk, const float* __restrict__ Wv,
    unsigned short* __restrict__ Wt, int* __restrict__ ctr) {

    const int t   = threadIdx.x;
    if (blockIdx.x == 0) ctr[t] = 0;        // 256 counters (b*32+qt)

    const int mat = blockIdx.x / 48;
    const int kb  = blockIdx.x % 48;
    const int h   = t & 63;
    const int k0  = (kb * 4 + (t >> 6)) * 4;

    const float* Ws = (mat == 0) ? Wq : (mat == 1) ? Wk : Wv;
    const float sc  = (mat == 0) ? LOG2E_SCALE : 1.f;
    ushort4 o;
    o.x = f2bf(Ws[(size_t)(k0 + 0) * H_ + h] * sc);
    o.y = f2bf(Ws[(size_t)(k0 + 1) * H_ + h] * sc);
    o.z = f2bf(Ws[(size_t)(k0 + 2) * H_ + h] * sc);
    o.w = f2bf(Ws[(size_t)(k0 + 3) * H_ + h] * sc);
    *reinterpret_cast<ushort4*>(&Wt[(size_t)(mat * 64 + h) * C_ + k0]) = o;
}

// ---------------------------------------------------------------------------
// Kernel 1: fused QKV projection, pipelined staging.
// 6 chunks of 128 k; LDS double buffer (2 x 16 KB); loads for chunk c+1
// issued before barrier+compute of chunk c -> HBM stream stays busy.
// One barrier per chunk (write c+1 goes to the other buffer).
// Epilogue writes Q row-major and K/V as fragment-ordered swizzled images.
// ---------------------------------------------------------------------------
__global__ __launch_bounds__(256) void proj_kernel(
    const float* __restrict__ x, const unsigned short* __restrict__ Wt,
    unsigned short* __restrict__ qkv) {

    __shared__ unsigned short Als[2][8192];   // 2 x 16 KB: [4 ksteps][512]

    const int tid = threadIdx.x;
    const int w   = tid >> 6;
    const int l   = tid & 63;
    const int lg  = l >> 4;
    const int lc  = l & 15;
    const int row0 = blockIdx.x * 64;

    const int sr   = tid >> 2;          // row 0..63
    const int so   = tid & 3;           // k-oct 0..3 within k-step
    const int srt  = sr >> 4;
    const int sr15 = sr & 15;
    const int sbase = (so * 16 + (sr15 ^ so)) * 8;

    f32x4 acc[4][3];
#pragma unroll
    for (int rt = 0; rt < 4; ++rt)
#pragma unroll
        for (int ct = 0; ct < 3; ++ct) acc[rt][ct] = (f32x4)0.f;

    const unsigned short* bbase[3];
#pragma unroll
    for (int ct = 0; ct < 3; ++ct)
        bbase[ct] = Wt + (size_t)(w * 48 + ct * 16 + lc) * C_ + lg * 8;

    const float* xrow = x + (size_t)(row0 + sr) * C_ + so * 8;

    float4 fa[4][2];
#pragma unroll
    for (int jj = 0; jj < 4; ++jj) {                    // issue chunk 0
        fa[jj][0] = *reinterpret_cast<const float4*>(xrow + jj * 32);
        fa[jj][1] = *reinterpret_cast<const float4*>(xrow + jj * 32 + 4);
    }

#pragma unroll
    for (int c = 0; c < 6; ++c) {
        // ---- convert + write chunk c into buffer c&1
#pragma unroll
        for (int jj = 0; jj < 4; ++jj) {
            short8 v;
            v[0] = (short)f2bf(fa[jj][0].x); v[1] = (short)f2bf(fa[jj][0].y);
            v[2] = (short)f2bf(fa[jj][0].z); v[3] = (short)f2bf(fa[jj][0].w);
            v[4] = (short)f2bf(fa[jj][1].x); v[5] = (short)f2bf(fa[jj][1].y);
            v[6] = (short)f2bf(fa[jj][1].z); v[7] = (short)f2bf(fa[jj][1].w);
            *reinterpret_cast<short8*>(&Als[c & 1][(srt * 4 + jj) * 512 + sbase]) = v;
        }
        // ---- issue chunk c+1 (flies during barrier + compute)
        if (c < 5) {
#pragma unroll
            for (int jj = 0; jj < 4; ++jj) {
                fa[jj][0] = *reinterpret_cast<const float4*>(xrow + (c + 1) * 128 + jj * 32);
                fa[jj][1] = *reinterpret_cast<const float4*>(xrow + (c + 1) * 128 + jj * 32 + 4);
            }
        }
        __syncthreads();
        // ---- compute chunk c (4 k-steps)
#pragma unroll
        for (int kk = 0; kk < 4; ++kk) {
            short8 bcur[3];
#pragma unroll
            for (int ct = 0; ct < 3; ++ct)
                bcur[ct] = *reinterpret_cast<const short8*>(bbase[ct] + c * 128 + kk * 32);
            short8 af[4];
#pragma unroll
            for (int rt = 0; rt < 4; ++rt)
                af[rt] = *reinterpret_cast<const short8*>(
                    &Als[c & 1][(rt * 4 + kk) * 512 + (lg * 16 + (lc ^ lg)) * 8]);
#pragma unroll
            for (int rt = 0; rt < 4; ++rt)
#pragma unroll
                for (int ct = 0; ct < 3; ++ct)
                    acc[rt][ct] = __builtin_amdgcn_mfma_f32_16x16x32_bf16(af[rt], bcur[ct], acc[rt][ct], 0, 0, 0);
        }
    }

    // ---- epilogue
    unsigned short* Qd   = qkv;
    unsigned short* Kimg = qkv + (size_t)M_ * H_;
    unsigned short* Vimg = qkv + (size_t)2 * M_ * H_;
    const size_t g12 = (size_t)blockIdx.x << 12;
#pragma unroll
    for (int ct = 0; ct < 3; ++ct) {
        const int col = w * 48 + ct * 16 + lc;
        const int mat = col >> 6;
        const int h   = col & 63;
        const int foh = fragoff(h);
#pragma unroll
        for (int rt = 0; rt < 4; ++rt)
#pragma unroll
            for (int j = 0; j < 4; ++j) {
                const int s6 = rt * 16 + lg * 4 + j;
                const unsigned short v = f2bf(acc[rt][ct][j]);
                if (mat == 0)      Qd[(size_t)(row0 + s6) * H_ + h] = v;
                else if (mat == 1) Kimg[g12 + swz(s6, foh)] = v;
                else               Vimg[g12 + swz(h, fragoff(s6))] = v;
            }
    }
}

// ---------------------------------------------------------------------------
// Segment bookkeeping for split-KV flash attention (KV tiles of 64 rows).
// ---------------------------------------------------------------------------
#define SEG_FLOATS 4224

template<int SEG>
static __device__ __forceinline__ int segs_per_batch() { return SEG == 32 ? 32 : 80; }

template<int SEG>
static __device__ __forceinline__ void decode_seg(int r, int& qt, int& seg) {
    if (SEG == 32) { qt = r; seg = 0; return; }
    if (r < 8)       { qt = r;                seg = 0; }
    else if (r < 24) { qt = 8  + (r - 8) / 2; seg = (r - 8) & 1; }
    else if (r < 48) { qt = 16 + (r - 24) / 3; seg = (r - 24) % 3; }
    else             { qt = 24 + (r - 48) / 4; seg = (r - 48) & 3; }
}

template<int SEG>
static __device__ __forceinline__ int seg_prefix(int qt) {
    if (SEG == 32) return qt;
    if (qt < 8)  return qt;
    if (qt < 16) return 8  + 2 * (qt - 8);
    if (qt < 24) return 24 + 3 * (qt - 16);
    return 48 + 4 * (qt - 24);
}

// ---------------------------------------------------------------------------
// Kernel 2: partial causal flash attention with in-kernel merge.
// Swapped-operand MFMA; single ds_read_b128 frags from fragment-ordered
// images; gload_lds double-buffer with counted vmcnt.  Multi-segment
// q-tiles: each block writes its partial, bumps an agent-scope counter;
// the LAST-arriving block merges all segments (no spinning -> no deadlock).
// ---------------------------------------------------------------------------
template<int SEG>
__global__ __launch_bounds__(256) void attn_partial(
    const unsigned short* __restrict__ qkv, float* __restrict__ part,
    float* __restrict__ out, int* __restrict__ ctr) {

    const int spb = segs_per_batch<SEG>();
    const int b   = blockIdx.x / spb;
    const int rr  = spb - 1 - (blockIdx.x % spb);   // longest blocks first
    int qt, seg;
    decode_seg<SEG>(rr, qt, seg);

    const int tid = threadIdx.x;
    const int w  = tid >> 6;
    const int l  = tid & 63;
    const int lg = l >> 4;
    const int lc = l & 15;

    __shared__ unsigned short Kls[2][4096];
    __shared__ unsigned short Vls[2][4096];
    __shared__ int lastFlag;

    const unsigned short* Qg = qkv;
    const unsigned short* Kg = qkv + (size_t)M_ * H_;
    const unsigned short* Vg = qkv + (size_t)2 * M_ * H_;

    const unsigned short* qrow = Qg + (size_t)(b * T_ + qt * 64 + w * 16 + lc) * H_;
    short8 qf[2];
#pragma unroll
    for (int ks = 0; ks < 2; ++ks)
        qf[ks] = make_frag(qrow + ks * 32 + lg * 4, qrow + ks * 32 + lg * 4 + 16);

    float mval = -1e30f, lsum = 0.f;
    f32x4 oT[4];
#pragma unroll
    for (int t = 0; t < 4; ++t) oT[t] = (f32x4)0.f;

    const int q_glob = qt * 64 + w * 16 + lc;

    const int kv_beg = seg * SEG;
    const int kv_end = min(kv_beg + SEG, qt + 1);

    const int go = w * 1024 + l * 8;

    auto stage = [&](int buf, int kv) {
        const size_t tb = ((size_t)(b * 32 + kv)) << 12;
        const unsigned short* kt = Kg + tb;
        const unsigned short* vt = Vg + tb;
        GLDS16(kt + go,       &Kls[buf][w * 1024]);
        GLDS16(kt + go + 512, &Kls[buf][w * 1024 + 512]);
        GLDS16(vt + go,       &Vls[buf][w * 1024]);
        GLDS16(vt + go + 512, &Vls[buf][w * 1024 + 512]);
    };

    stage(0, kv_beg);
    int cur = 0;

    for (int kv = kv_beg; kv < kv_end; ++kv) {
        const bool more = (kv + 1 < kv_end);
        __builtin_amdgcn_s_barrier();              // (A) prev compute done
        asm volatile("" ::: "memory");
        if (more) {
            stage(cur ^ 1, kv + 1);
            asm volatile("s_waitcnt vmcnt(4)" ::: "memory");
        } else {
            asm volatile("s_waitcnt vmcnt(0)" ::: "memory");
        }
        __builtin_amdgcn_s_barrier();              // (B) cur tile resident
        asm volatile("" ::: "memory");

        const unsigned short* Kc = Kls[cur];
        const unsigned short* Vc = Vls[cur];

        // ---- S^T = (K Q^T), already in log2 domain
        f32x4 sT[4];
#pragma unroll
        for (int st = 0; st < 4; ++st) {
            f32x4 accs = (f32x4)0.f;
#pragma unroll
            for (int ks = 0; ks < 2; ++ks) {
                const short8 kf = *reinterpret_cast<const short8*>(
                    &Kc[swz(st * 16 + lc, (ks * 4 + lg) * 8)]);
                accs = __builtin_amdgcn_mfma_f32_16x16x32_bf16(kf, qf[ks], accs, 0, 0, 0);
            }
            sT[st] = accs;
        }

        float p[4][4];
#pragma unroll
        for (int st = 0; st < 4; ++st)
#pragma unroll
            for (int r = 0; r < 4; ++r)
                p[st][r] = sT[st][r];

        if (kv == qt) {
#pragma unroll
            for (int st = 0; st < 4; ++st)
#pragma unroll
                for (int r = 0; r < 4; ++r)
                    if ((kv * 64 + st * 16 + lg * 4 + r) > q_glob) p[st][r] = -1e30f;
        }

        float pm[4];
#pragma unroll
        for (int st = 0; st < 4; ++st)
            pm[st] = fmaxf(fmaxf(p[st][0], p[st][1]), fmaxf(p[st][2], p[st][3]));
        float pmax = fmaxf(fmaxf(pm[0], pm[1]), fmaxf(pm[2], pm[3]));
        pmax = fmaxf(pmax, __shfl_xor(pmax, 16));
        pmax = fmaxf(pmax, __shfl_xor(pmax, 32));

        if (!__all(pmax <= mval)) {                // exact defer-rescale
            const float mnew  = fmaxf(mval, pmax);
            const float alpha = exp2f(mval - mnew);
            mval = mnew;
            lsum *= alpha;
#pragma unroll
            for (int ht = 0; ht < 4; ++ht) oT[ht] *= alpha;
        }

        float ps[4];
#pragma unroll
        for (int st = 0; st < 4; ++st) {
#pragma unroll
            for (int r = 0; r < 4; ++r)
                p[st][r] = exp2f(p[st][r] - mval);
            ps[st] = (p[st][0] + p[st][1]) + (p[st][2] + p[st][3]);
        }
        float srow = (ps[0] + ps[1]) + (ps[2] + ps[3]);
        srow += __shfl_xor(srow, 16);
        srow += __shfl_xor(srow, 32);
        lsum += srow;

        short8 pb[2];
#pragma unroll
        for (int ks = 0; ks < 2; ++ks) {
#pragma unroll
            for (int r = 0; r < 4; ++r) {
                pb[ks][r]     = (short)f2bf(p[2 * ks][r]);
                pb[ks][r + 4] = (short)f2bf(p[2 * ks + 1][r]);
            }
        }

#pragma unroll
        for (int ks = 0; ks < 2; ++ks) {
#pragma unroll
            for (int ht = 0; ht < 4; ++ht) {
                const short8 vf = *reinterpret_cast<const short8*>(
                    &Vc[swz(ht * 16 + lc, (ks * 4 + lg) * 8)]);
                oT[ht] = __builtin_amdgcn_mfma_f32_16x16x32_bf16(vf, pb[ks], oT[ht], 0, 0, 0);
            }
        }
        cur ^= 1;
    }

    const int nseg = (SEG == 32) ? 1 : (qt / 8 + 1);
    if (nseg == 1) {
        const float inv = 1.f / lsum;
        float* op = out + (size_t)(b * T_ + q_glob) * H_;
#pragma unroll
        for (int ht = 0; ht < 4; ++ht) {
            f32x4 v = oT[ht] * inv;
            *reinterpret_cast<f32x4*>(&op[ht * 16 + lg * 4]) = v;
        }
        return;
    }

    // ---- multi-segment: publish partial, last arrival merges
    float* base = part + (size_t)(b * spb + seg_prefix<SEG>(qt) + seg) * SEG_FLOATS;
#pragma unroll
    for (int ht = 0; ht < 4; ++ht)
        *reinterpret_cast<f32x4*>(&base[(w * 16 + lc) * 64 + ht * 16 + lg * 4]) = oT[ht];
    if (lg == 0) {
        base[4096 + w * 16 + lc] = mval;
        base[4160 + w * 16 + lc] = lsum;
    }
    __threadfence();
    __syncthreads();
    if (tid == 0) {
        const int old = __hip_atomic_fetch_add(&ctr[b * 32 + qt], 1,
                                               __ATOMIC_ACQ_REL, __HIP_MEMORY_SCOPE_AGENT);
        lastFlag = (old == nseg - 1);
    }
    __syncthreads();
    if (!lastFlag) return;
    __threadfence();

    // ---- merge all segments of (b, qt); deterministic order s = 0..nseg-1
    const int row = tid >> 2;
    const int c0  = (tid & 3) * 16;
    const float* base0 = part + (size_t)(b * spb + seg_prefix<SEG>(qt)) * SEG_FLOATS;

    float Mx = -1e30f;
    for (int s = 0; s < nseg; ++s)
        Mx = fmaxf(Mx, base0[(size_t)s * SEG_FLOATS + 4096 + row]);

    float L = 0.f;
    f32x4 acc[4];
#pragma unroll
    for (int k = 0; k < 4; ++k) acc[k] = (f32x4)0.f;

    for (int s = 0; s < nseg; ++s) {
        const float* sb = base0 + (size_t)s * SEG_FLOATS;
        const float wsc = exp2f(sb[4096 + row] - Mx);
        L += sb[4160 + row] * wsc;
#pragma unroll
        for (int k = 0; k < 4; ++k) {
            const f32x4 ov = *reinterpret_cast<const f32x4*>(&sb[row * 64 + c0 + 4 * k]);
            acc[k] += ov * wsc;
        }
    }
    const float inv = 1.f / L;
    float* op = out + (size_t)(b * T_ + qt * 64 + row) * H_ + c0;
#pragma unroll
    for (int k = 0; k < 4; ++k)
        *reinterpret_cast<f32x4*>(&op[4 * k]) = acc[k] * inv;
}

extern "C" void kernel_launch(void* const* d_in, const int* in_sizes, int n_in,
                              void* d_out, int out_size, void* d_ws, size_t ws_size,
                              hipStream_t stream) {
    const float* x  = (const float*)d_in[0];
    const float* Wk = (const float*)d_in[1];
    const float* Wq = (const float*)d_in[2];
    const float* Wv = (const float*)d_in[3];

    const size_t qkvB  = (size_t)3 * M_ * H_ * 2;          // 6,291,456
    const size_t WtB   = (size_t)3 * H_ * C_ * 2;          //   294,912
    const size_t partB = (size_t)(B_ * 80) * SEG_FLOATS * 4;
    unsigned short* qkv = (unsigned short*)d_ws;
    unsigned short* Wt  = (unsigned short*)((char*)d_ws + qkvB);
    float* part = (float*)((char*)d_ws + qkvB + WtB);
    int*   ctr  = (int*)((char*)d_ws + qkvB + WtB + partB);
    float* out  = (float*)d_out;

    prep_w<<<dim3(144), dim3(256), 0, stream>>>(Wq, Wk, Wv, Wt, ctr);
    proj_kernel<<<dim3(M_ / 64), dim3(256), 0, stream>>>(x, Wt, qkv);

    const size_t need8 = qkvB + WtB + partB + 256 * sizeof(int);
    if (ws_size >= need8) {
        attn_partial<8><<<dim3(B_ * 80), dim3(256), 0, stream>>>(qkv, part, out, ctr);
    } else {
        // SEG=32: every q-tile is a single segment -> direct write, no merge
        attn_partial<32><<<dim3(B_ * 32), dim3(256), 0, stream>>>(qkv, part, out, ctr);
    }
}

// Round 9
// 56.120 us; speedup vs baseline: 3.0220x; 3.0220x over previous
//
#include <hip/hip_runtime.h>
#include <hip/hip_bf16.h>

typedef __attribute__((ext_vector_type(8))) short short8;
typedef __attribute__((ext_vector_type(4))) float f32x4;

#define B_  8
#define T_  2048
#define C_  768
#define H_  64
#define M_  (B_ * T_)   // 16384 rows

// direct global -> LDS, 16 B per lane; LDS dest must be wave-uniform base.
#define GLDS16(g, l) __builtin_amdgcn_global_load_lds(                        \
    (const __attribute__((address_space(1))) void*)(g),                       \
    (__attribute__((address_space(3))) void*)(l), 16, 0, 0)

static __device__ __forceinline__ unsigned short f2bf(float f) {
    __hip_bfloat16 h = __float2bfloat16(f);
    return *reinterpret_cast<unsigned short*>(&h);
}

static __device__ __forceinline__ short8 make_frag(const unsigned short* p0, const unsigned short* p1) {
    const ushort4 a = *reinterpret_cast<const ushort4*>(p0);
    const ushort4 b = *reinterpret_cast<const ushort4*>(p1);
    short8 r;
    r[0] = (short)a.x; r[1] = (short)a.y; r[2] = (short)a.z; r[3] = (short)a.w;
    r[4] = (short)b.x; r[5] = (short)b.y; r[6] = (short)b.z; r[7] = (short)b.w;
    return r;
}

// XOR swizzle for 64-ushort (128 B) rows: permute 16 B chunk idx with row&7.
static __device__ __forceinline__ int swz(int row, int u) {
    return row * 64 + ((((u) >> 3) ^ (row & 7)) << 3) + (u & 7);
}

// Fragment-order position of element k (0..63) within a 64-elem image row.
static __device__ __forceinline__ int fragoff(int k) {
    const int half = k >> 5;
    const int kk   = k & 31;
    const int c    = half * 4 + ((kk >> 2) & 3);
    const int p    = (kk & 3) + ((kk & 16) >> 2);
    return c * 8 + p;
}

#define LOG2E_SCALE 0.18033688011112042f   // 0.125 * log2(e), folded into Wq

// ---------------------------------------------------------------------------
// Kernel 0: W -> Wt (transpose + fp32->bf16), Wq pre-scaled.
// ---------------------------------------------------------------------------
__global__ __launch_bounds__(256) void prep_w(
    const float* __restrict__ Wq, const float* __restrict__ Wk, const float* __restrict__ Wv,
    unsigned short* __restrict__ Wt) {

    const int t   = threadIdx.x;
    const int mat = blockIdx.x / 48;
    const int kb  = blockIdx.x % 48;
    const int h   = t & 63;
    const int k0  = (kb * 4 + (t >> 6)) * 4;

    const float* Ws = (mat == 0) ? Wq : (mat == 1) ? Wk : Wv;
    const float sc  = (mat == 0) ? LOG2E_SCALE : 1.f;
    ushort4 o;
    o.x = f2bf(Ws[(size_t)(k0 + 0) * H_ + h] * sc);
    o.y = f2bf(Ws[(size_t)(k0 + 1) * H_ + h] * sc);
    o.z = f2bf(Ws[(size_t)(k0 + 2) * H_ + h] * sc);
    o.w = f2bf(Ws[(size_t)(k0 + 3) * H_ + h] * sc);
    *reinterpret_cast<ushort4*>(&Wt[(size_t)(mat * 64 + h) * C_ + k0]) = o;
}

// ---------------------------------------------------------------------------
// Kernel 1: fused QKV projection, pipelined staging (round-8 version, kept).
// 6 chunks of 128 k; LDS double buffer (2 x 16 KB); loads for chunk c+1
// issued before barrier+compute of chunk c -> HBM stream stays busy.
// Epilogue writes Q row-major and K/V as fragment-ordered swizzled images.
// ---------------------------------------------------------------------------
__global__ __launch_bounds__(256) void proj_kernel(
    const float* __restrict__ x, const unsigned short* __restrict__ Wt,
    unsigned short* __restrict__ qkv) {

    __shared__ unsigned short Als[2][8192];   // 2 x 16 KB: [4 ksteps][512]

    const int tid = threadIdx.x;
    const int w   = tid >> 6;
    const int l   = tid & 63;
    const int lg  = l >> 4;
    const int lc  = l & 15;
    const int row0 = blockIdx.x * 64;

    const int sr   = tid >> 2;          // row 0..63
    const int so   = tid & 3;           // k-oct 0..3 within k-step
    const int srt  = sr >> 4;
    const int sr15 = sr & 15;
    const int sbase = (so * 16 + (sr15 ^ so)) * 8;

    f32x4 acc[4][3];
#pragma unroll
    for (int rt = 0; rt < 4; ++rt)
#pragma unroll
        for (int ct = 0; ct < 3; ++ct) acc[rt][ct] = (f32x4)0.f;

    const unsigned short* bbase[3];
#pragma unroll
    for (int ct = 0; ct < 3; ++ct)
        bbase[ct] = Wt + (size_t)(w * 48 + ct * 16 + lc) * C_ + lg * 8;

    const float* xrow = x + (size_t)(row0 + sr) * C_ + so * 8;

    float4 fa[4][2];
#pragma unroll
    for (int jj = 0; jj < 4; ++jj) {                    // issue chunk 0
        fa[jj][0] = *reinterpret_cast<const float4*>(xrow + jj * 32);
        fa[jj][1] = *reinterpret_cast<const float4*>(xrow + jj * 32 + 4);
    }

#pragma unroll
    for (int c = 0; c < 6; ++c) {
        // ---- convert + write chunk c into buffer c&1
#pragma unroll
        for (int jj = 0; jj < 4; ++jj) {
            short8 v;
            v[0] = (short)f2bf(fa[jj][0].x); v[1] = (short)f2bf(fa[jj][0].y);
            v[2] = (short)f2bf(fa[jj][0].z); v[3] = (short)f2bf(fa[jj][0].w);
            v[4] = (short)f2bf(fa[jj][1].x); v[5] = (short)f2bf(fa[jj][1].y);
            v[6] = (short)f2bf(fa[jj][1].z); v[7] = (short)f2bf(fa[jj][1].w);
            *reinterpret_cast<short8*>(&Als[c & 1][(srt * 4 + jj) * 512 + sbase]) = v;
        }
        // ---- issue chunk c+1 (flies during barrier + compute)
        if (c < 5) {
#pragma unroll
            for (int jj = 0; jj < 4; ++jj) {
                fa[jj][0] = *reinterpret_cast<const float4*>(xrow + (c + 1) * 128 + jj * 32);
                fa[jj][1] = *reinterpret_cast<const float4*>(xrow + (c + 1) * 128 + jj * 32 + 4);
            }
        }
        __syncthreads();
        // ---- compute chunk c (4 k-steps)
#pragma unroll
        for (int kk = 0; kk < 4; ++kk) {
            short8 bcur[3];
#pragma unroll
            for (int ct = 0; ct < 3; ++ct)
                bcur[ct] = *reinterpret_cast<const short8*>(bbase[ct] + c * 128 + kk * 32);
            short8 af[4];
#pragma unroll
            for (int rt = 0; rt < 4; ++rt)
                af[rt] = *reinterpret_cast<const short8*>(
                    &Als[c & 1][(rt * 4 + kk) * 512 + (lg * 16 + (lc ^ lg)) * 8]);
#pragma unroll
            for (int rt = 0; rt < 4; ++rt)
#pragma unroll
                for (int ct = 0; ct < 3; ++ct)
                    acc[rt][ct] = __builtin_amdgcn_mfma_f32_16x16x32_bf16(af[rt], bcur[ct], acc[rt][ct], 0, 0, 0);
        }
    }

    // ---- epilogue
    unsigned short* Qd   = qkv;
    unsigned short* Kimg = qkv + (size_t)M_ * H_;
    unsigned short* Vimg = qkv + (size_t)2 * M_ * H_;
    const size_t g12 = (size_t)blockIdx.x << 12;
#pragma unroll
    for (int ct = 0; ct < 3; ++ct) {
        const int col = w * 48 + ct * 16 + lc;
        const int mat = col >> 6;
        const int h   = col & 63;
        const int foh = fragoff(h);
#pragma unroll
        for (int rt = 0; rt < 4; ++rt)
#pragma unroll
            for (int j = 0; j < 4; ++j) {
                const int s6 = rt * 16 + lg * 4 + j;
                const unsigned short v = f2bf(acc[rt][ct][j]);
                if (mat == 0)      Qd[(size_t)(row0 + s6) * H_ + h] = v;
                else if (mat == 1) Kimg[g12 + swz(s6, foh)] = v;
                else               Vimg[g12 + swz(h, fragoff(s6))] = v;
            }
    }
}

// ---------------------------------------------------------------------------
// Segment bookkeeping for split-KV flash attention (KV tiles of 64 rows).
// ---------------------------------------------------------------------------
#define SEG_FLOATS 4224

template<int SEG>
static __device__ __forceinline__ int segs_per_batch() { return SEG == 32 ? 32 : 80; }

template<int SEG>
static __device__ __forceinline__ void decode_seg(int r, int& qt, int& seg) {
    if (SEG == 32) { qt = r; seg = 0; return; }
    if (r < 8)       { qt = r;                seg = 0; }
    else if (r < 24) { qt = 8  + (r - 8) / 2; seg = (r - 8) & 1; }
    else if (r < 48) { qt = 16 + (r - 24) / 3; seg = (r - 24) % 3; }
    else             { qt = 24 + (r - 48) / 4; seg = (r - 48) & 3; }
}

template<int SEG>
static __device__ __forceinline__ int seg_prefix(int qt) {
    if (SEG == 32) return qt;
    if (qt < 8)  return qt;
    if (qt < 16) return 8  + 2 * (qt - 8);
    if (qt < 24) return 24 + 3 * (qt - 16);
    return 48 + 4 * (qt - 24);
}

// ---------------------------------------------------------------------------
// Kernel 2a: partial causal flash attention (round-7 structure: NO atomics,
// NO device-scope fences — per-XCD L2 coherence trap).  Swapped-operand MFMA;
// single ds_read_b128 frags from fragment-ordered images; gload_lds
// double-buffer with counted vmcnt; longest blocks first; single-segment
// q-tiles write normalized output directly.
// ---------------------------------------------------------------------------
template<int SEG>
__global__ __launch_bounds__(256) void attn_partial(
    const unsigned short* __restrict__ qkv, float* __restrict__ part,
    float* __restrict__ out) {

    const int spb = segs_per_batch<SEG>();
    const int b   = blockIdx.x / spb;
    const int rr  = spb - 1 - (blockIdx.x % spb);   // longest blocks first
    int qt, seg;
    decode_seg<SEG>(rr, qt, seg);

    const int tid = threadIdx.x;
    const int w  = tid >> 6;
    const int l  = tid & 63;
    const int lg = l >> 4;
    const int lc = l & 15;

    __shared__ unsigned short Kls[2][4096];
    __shared__ unsigned short Vls[2][4096];

    const unsigned short* Qg = qkv;
    const unsigned short* Kg = qkv + (size_t)M_ * H_;
    const unsigned short* Vg = qkv + (size_t)2 * M_ * H_;

    const unsigned short* qrow = Qg + (size_t)(b * T_ + qt * 64 + w * 16 + lc) * H_;
    short8 qf[2];
#pragma unroll
    for (int ks = 0; ks < 2; ++ks)
        qf[ks] = make_frag(qrow + ks * 32 + lg * 4, qrow + ks * 32 + lg * 4 + 16);

    float mval = -1e30f, lsum = 0.f;
    f32x4 oT[4];
#pragma unroll
    for (int t = 0; t < 4; ++t) oT[t] = (f32x4)0.f;

    const int q_glob = qt * 64 + w * 16 + lc;

    const int kv_beg = seg * SEG;
    const int kv_end = min(kv_beg + SEG, qt + 1);

    const int go = w * 1024 + l * 8;

    auto stage = [&](int buf, int kv) {
        const size_t tb = ((size_t)(b * 32 + kv)) << 12;
        const unsigned short* kt = Kg + tb;
        const unsigned short* vt = Vg + tb;
        GLDS16(kt + go,       &Kls[buf][w * 1024]);
        GLDS16(kt + go + 512, &Kls[buf][w * 1024 + 512]);
        GLDS16(vt + go,       &Vls[buf][w * 1024]);
        GLDS16(vt + go + 512, &Vls[buf][w * 1024 + 512]);
    };

    stage(0, kv_beg);
    int cur = 0;

    for (int kv = kv_beg; kv < kv_end; ++kv) {
        const bool more = (kv + 1 < kv_end);
        __builtin_amdgcn_s_barrier();              // (A) prev compute done
        asm volatile("" ::: "memory");
        if (more) {
            stage(cur ^ 1, kv + 1);
            asm volatile("s_waitcnt vmcnt(4)" ::: "memory");
        } else {
            asm volatile("s_waitcnt vmcnt(0)" ::: "memory");
        }
        __builtin_amdgcn_s_barrier();              // (B) cur tile resident
        asm volatile("" ::: "memory");

        const unsigned short* Kc = Kls[cur];
        const unsigned short* Vc = Vls[cur];

        // ---- S^T = (K Q^T), already in log2 domain
        f32x4 sT[4];
#pragma unroll
        for (int st = 0; st < 4; ++st) {
            f32x4 accs = (f32x4)0.f;
#pragma unroll
            for (int ks = 0; ks < 2; ++ks) {
                const short8 kf = *reinterpret_cast<const short8*>(
                    &Kc[swz(st * 16 + lc, (ks * 4 + lg) * 8)]);
                accs = __builtin_amdgcn_mfma_f32_16x16x32_bf16(kf, qf[ks], accs, 0, 0, 0);
            }
            sT[st] = accs;
        }

        float p[4][4];
#pragma unroll
        for (int st = 0; st < 4; ++st)
#pragma unroll
            for (int r = 0; r < 4; ++r)
                p[st][r] = sT[st][r];

        if (kv == qt) {
#pragma unroll
            for (int st = 0; st < 4; ++st)
#pragma unroll
                for (int r = 0; r < 4; ++r)
                    if ((kv * 64 + st * 16 + lg * 4 + r) > q_glob) p[st][r] = -1e30f;
        }

        float pm[4];
#pragma unroll
        for (int st = 0; st < 4; ++st)
            pm[st] = fmaxf(fmaxf(p[st][0], p[st][1]), fmaxf(p[st][2], p[st][3]));
        float pmax = fmaxf(fmaxf(pm[0], pm[1]), fmaxf(pm[2], pm[3]));
        pmax = fmaxf(pmax, __shfl_xor(pmax, 16));
        pmax = fmaxf(pmax, __shfl_xor(pmax, 32));

        if (!__all(pmax <= mval)) {                // exact defer-rescale
            const float mnew  = fmaxf(mval, pmax);
            const float alpha = exp2f(mval - mnew);
            mval = mnew;
            lsum *= alpha;
#pragma unroll
            for (int ht = 0; ht < 4; ++ht) oT[ht] *= alpha;
        }

        float ps[4];
#pragma unroll
        for (int st = 0; st < 4; ++st) {
#pragma unroll
            for (int r = 0; r < 4; ++r)
                p[st][r] = exp2f(p[st][r] - mval);
            ps[st] = (p[st][0] + p[st][1]) + (p[st][2] + p[st][3]);
        }
        float srow = (ps[0] + ps[1]) + (ps[2] + ps[3]);
        srow += __shfl_xor(srow, 16);
        srow += __shfl_xor(srow, 32);
        lsum += srow;

        short8 pb[2];
#pragma unroll
        for (int ks = 0; ks < 2; ++ks) {
#pragma unroll
            for (int r = 0; r < 4; ++r) {
                pb[ks][r]     = (short)f2bf(p[2 * ks][r]);
                pb[ks][r + 4] = (short)f2bf(p[2 * ks + 1][r]);
            }
        }

#pragma unroll
        for (int ks = 0; ks < 2; ++ks) {
#pragma unroll
            for (int ht = 0; ht < 4; ++ht) {
                const short8 vf = *reinterpret_cast<const short8*>(
                    &Vc[swz(ht * 16 + lc, (ks * 4 + lg) * 8)]);
                oT[ht] = __builtin_amdgcn_mfma_f32_16x16x32_bf16(vf, pb[ks], oT[ht], 0, 0, 0);
            }
        }
        cur ^= 1;
    }

    const int nseg = (SEG == 32) ? 1 : (qt / 8 + 1);
    if (nseg == 1) {
        // single segment: write normalized output directly
        const float inv = 1.f / lsum;
        float* op = out + (size_t)(b * T_ + q_glob) * H_;
#pragma unroll
        for (int ht = 0; ht < 4; ++ht) {
            f32x4 v = oT[ht] * inv;
            *reinterpret_cast<f32x4*>(&op[ht * 16 + lg * 4]) = v;
        }
    } else {
        float* base = part + (size_t)(b * spb + seg_prefix<SEG>(qt) + seg) * SEG_FLOATS;
#pragma unroll
        for (int ht = 0; ht < 4; ++ht)
            *reinterpret_cast<f32x4*>(&base[(w * 16 + lc) * 64 + ht * 16 + lg * 4]) = oT[ht];
        if (lg == 0) {
            base[4096 + w * 16 + lc] = mval;
            base[4160 + w * 16 + lc] = lsum;
        }
    }
}

// ---------------------------------------------------------------------------
// Kernel 2b: merge multi-segment q-tiles (qt >= 8), SEG=8 only.
// Grid = B_ * 24 blocks.
// ---------------------------------------------------------------------------
__global__ __launch_bounds__(256) void attn_merge8(
    const float* __restrict__ part, float* __restrict__ out) {

    const int b  = blockIdx.x / 24;
    const int qt = 8 + blockIdx.x % 24;
    const int nseg = qt / 8 + 1;
    const float* base0 = part + (size_t)(b * 80 + seg_prefix<8>(qt)) * SEG_FLOATS;

    const int tid = threadIdx.x;
    const int row = tid >> 2;
    const int c0  = (tid & 3) * 16;

    float M = -1e30f;
    for (int s = 0; s < nseg; ++s)
        M = fmaxf(M, base0[(size_t)s * SEG_FLOATS + 4096 + row]);

    float L = 0.f;
    f32x4 acc[4];
#pragma unroll
    for (int k = 0; k < 4; ++k) acc[k] = (f32x4)0.f;

    for (int s = 0; s < nseg; ++s) {
        const float* sb = base0 + (size_t)s * SEG_FLOATS;
        const float wsc = exp2f(sb[4096 + row] - M);
        L += sb[4160 + row] * wsc;
#pragma unroll
        for (int k = 0; k < 4; ++k) {
            const f32x4 ov = *reinterpret_cast<const f32x4*>(&sb[row * 64 + c0 + 4 * k]);
            acc[k] += ov * wsc;
        }
    }
    const float inv = 1.f / L;
    float* op = out + (size_t)(b * T_ + qt * 64 + row) * H_ + c0;
#pragma unroll
    for (int k = 0; k < 4; ++k)
        *reinterpret_cast<f32x4*>(&op[4 * k]) = acc[k] * inv;
}

extern "C" void kernel_launch(void* const* d_in, const int* in_sizes, int n_in,
                              void* d_out, int out_size, void* d_ws, size_t ws_size,
                              hipStream_t stream) {
    const float* x  = (const float*)d_in[0];
    const float* Wk = (const float*)d_in[1];
    const float* Wq = (const float*)d_in[2];
    const float* Wv = (const float*)d_in[3];

    const size_t qkvB = (size_t)3 * M_ * H_ * 2;          // 6,291,456
    const size_t WtB  = (size_t)3 * H_ * C_ * 2;          //   294,912
    unsigned short* qkv = (unsigned short*)d_ws;
    unsigned short* Wt  = (unsigned short*)((char*)d_ws + qkvB);
    float* part = (float*)((char*)d_ws + qkvB + WtB);
    float* out  = (float*)d_out;

    prep_w<<<dim3(144), dim3(256), 0, stream>>>(Wq, Wk, Wv, Wt);
    proj_kernel<<<dim3(M_ / 64), dim3(256), 0, stream>>>(x, Wt, qkv);

    const size_t need8 = qkvB + WtB + (size_t)(B_ * 80) * SEG_FLOATS * 4;
    if (ws_size >= need8) {
        attn_partial<8><<<dim3(B_ * 80), dim3(256), 0, stream>>>(qkv, part, out);
        attn_merge8<<<dim3(B_ * 24), dim3(256), 0, stream>>>(part, out);
    } else {
        // SEG=32: every q-tile is a single segment -> direct write, no merge
        attn_partial<32><<<dim3(B_ * 32), dim3(256), 0, stream>>>(qkv, part, out);
    }
}